// Round 2
// baseline (260.048 us; speedup 1.0000x reference)
//
#include <hip/hip_runtime.h>
#include <stdint.h>

#define B_N 1024
#define K_N 64
#define O_N 4096
#define I_N 4096

// ---------------------------------------------------------------------------
// Transpose W (O x I) -> WT (I x O). 64x64 tiles, float4 global loads/stores,
// LDS padded to 65 (scalar LDS ops, 2-way bank aliasing only = free).
// ---------------------------------------------------------------------------
__global__ __launch_bounds__(256) void transpose_kernel(
    const float* __restrict__ W, float* __restrict__ WT) {
  __shared__ float tile[64][65];
  const int t = threadIdx.x;
  const int tx = t & 15;   // float4 position along fast dim
  const int ty = t >> 4;   // 0..15
  const int i0 = blockIdx.x * 64;
  const int o0 = blockIdx.y * 64;
#pragma unroll
  for (int r = 0; r < 4; ++r) {
    const int o = ty + r * 16;
    const float4 v =
        *(const float4*)(W + (size_t)(o0 + o) * I_N + i0 + 4 * tx);
    tile[o][4 * tx + 0] = v.x;
    tile[o][4 * tx + 1] = v.y;
    tile[o][4 * tx + 2] = v.z;
    tile[o][4 * tx + 3] = v.w;
  }
  __syncthreads();
#pragma unroll
  for (int r = 0; r < 4; ++r) {
    const int i = ty + r * 16;
    float4 v;
    v.x = tile[4 * tx + 0][i];
    v.y = tile[4 * tx + 1][i];
    v.z = tile[4 * tx + 2][i];
    v.w = tile[4 * tx + 3][i];
    *(float4*)(WT + (size_t)(i0 + i) * O_N + o0 + 4 * tx) = v;
  }
}

#define ACC4(a, c, xk)                         \
  a.x = __fadd_rn(a.x, __fmul_rn(xk, c.x));    \
  a.y = __fadd_rn(a.y, __fmul_rn(xk, c.y));    \
  a.z = __fadd_rn(a.z, __fmul_rn(xk, c.z));    \
  a.w = __fadd_rn(a.w, __fmul_rn(xk, c.w));

// ---------------------------------------------------------------------------
// Phase 1: gathered matvec, O split in halves -> 2048 blocks, depth-2
// register pipeline. Bit-exact: ascending-k chain, unfused mul/add,
// bias added last.
// ---------------------------------------------------------------------------
__global__ __launch_bounds__(256) void gemv_phase(
    const float* __restrict__ x, const float* __restrict__ WT,
    const float* __restrict__ bias, const int* __restrict__ idx,
    float* __restrict__ res) {
  __shared__ float sx[K_N];
  __shared__ int si[K_N];
  const int t = threadIdx.x;
  const int bb = blockIdx.x;
  const int b = bb >> 1;
  const int half = bb & 1;
  if (t < K_N) {
    sx[t] = x[b * K_N + t];
    si[t] = idx[b * K_N + t];
  }
  __syncthreads();

  const size_t hoff = (size_t)half * 2048;
  const int g0 = t;
  const int g1 = t + 256;
  float4 a0 = make_float4(0.f, 0.f, 0.f, 0.f);
  float4 a1 = make_float4(0.f, 0.f, 0.f, 0.f);

  const float4* r0 = (const float4*)(WT + (size_t)si[0] * O_N + hoff);
  float4 p0 = r0[g0];
  float4 p1 = r0[g1];
  for (int k = 0; k < K_N; ++k) {
    const float4 c0 = p0;
    const float4 c1 = p1;
    if (k + 1 < K_N) {
      const float4* rn =
          (const float4*)(WT + (size_t)si[k + 1] * O_N + hoff);
      p0 = rn[g0];
      p1 = rn[g1];
    }
    const float xk = sx[k];
    ACC4(a0, c0, xk);
    ACC4(a1, c1, xk);
  }
  const float4 b0 = ((const float4*)bias)[half * 512 + g0];
  const float4 b1 = ((const float4*)bias)[half * 512 + g1];
  a0.x = __fadd_rn(a0.x, b0.x);
  a0.y = __fadd_rn(a0.y, b0.y);
  a0.z = __fadd_rn(a0.z, b0.z);
  a0.w = __fadd_rn(a0.w, b0.w);
  a1.x = __fadd_rn(a1.x, b1.x);
  a1.y = __fadd_rn(a1.y, b1.y);
  a1.z = __fadd_rn(a1.z, b1.z);
  a1.w = __fadd_rn(a1.w, b1.w);
  float4* ro = (float4*)(res + (size_t)b * O_N + hoff);
  ro[g0] = a0;
  ro[g1] = a1;
}

// ---------------------------------------------------------------------------
// Phase 2: exact top-64 per row (radix select + 64-lane bitonic; ties ->
// lower index first). Keys loaded straight from global to registers.
// ---------------------------------------------------------------------------
__global__ __launch_bounds__(256) void topk_phase(
    const float* __restrict__ res, float* __restrict__ out) {
  __shared__ unsigned int hist[256];
  __shared__ unsigned int scan[256];
  __shared__ unsigned int sel_u[64];
  __shared__ int sel_i[64];
  __shared__ int eqlist[128];
  __shared__ unsigned int s_T, s_ngt, s_cntgt, s_cnteq;
  __shared__ unsigned int s_remaining, s_prefix;

  const int t = threadIdx.x;
  const int b = blockIdx.x;
  if (t == 0) {
    s_remaining = 64u;
    s_prefix = 0u;
    s_cntgt = 0u;
    s_cnteq = 0u;
  }

  unsigned int myu[16];
#pragma unroll
  for (int j = 0; j < 16; ++j) {
    const float f = res[(size_t)b * O_N + t + 256 * j];
    const unsigned int s = __float_as_uint(f);
    myu[j] = (s & 0x80000000u) ? ~s : (s | 0x80000000u);
  }

  for (int round = 3; round >= 0; --round) {
    const int shift = round * 8;
    hist[t] = 0u;
    __syncthreads();
    const unsigned int pfx = s_prefix;
    const unsigned int rem = s_remaining;
    const unsigned int himask =
        (round == 3) ? 0u : (0xFFFFFFFFu << (shift + 8));
#pragma unroll
    for (int j = 0; j < 16; ++j) {
      if ((myu[j] & himask) == (pfx & himask))
        atomicAdd(&hist[(myu[j] >> shift) & 255u], 1u);
    }
    __syncthreads();
    scan[t] = hist[t];
    __syncthreads();
    for (int off = 1; off < 256; off <<= 1) {
      unsigned int v = (t + off < 256) ? scan[t + off] : 0u;
      __syncthreads();
      scan[t] += v;
      __syncthreads();
    }
    const unsigned int c_ge = scan[t];
    const unsigned int c_gt = (t < 255) ? scan[t + 1] : 0u;
    if (c_ge >= rem && c_gt < rem) {
      s_T = (unsigned int)t;
      s_ngt = c_gt;
    }
    __syncthreads();
    if (t == 0) {
      s_prefix |= (s_T << shift);
      s_remaining -= s_ngt;
    }
    __syncthreads();
  }
  const unsigned int ustar = s_prefix;

#pragma unroll
  for (int j = 0; j < 16; ++j) {
    const unsigned int u = myu[j];
    if (u > ustar) {
      unsigned int p = atomicAdd(&s_cntgt, 1u);
      sel_u[p] = u;
      sel_i[p] = t + 256 * j;
    } else if (u == ustar) {
      unsigned int p = atomicAdd(&s_cnteq, 1u);
      if (p < 128u) eqlist[p] = t + 256 * j;
    }
  }
  __syncthreads();

  if (t == 0 && s_cnteq > 1u) {
    int n = (int)(s_cnteq < 128u ? s_cnteq : 128u);
    for (int a = 1; a < n; ++a) {
      int v = eqlist[a];
      int c = a;
      while (c > 0 && eqlist[c - 1] > v) {
        eqlist[c] = eqlist[c - 1];
        --c;
      }
      eqlist[c] = v;
    }
  }
  __syncthreads();

  if (t < 64) {
    const int n_gt = (int)s_cntgt;
    unsigned int u;
    int oi;
    if (t < n_gt) {
      u = sel_u[t];
      oi = sel_i[t];
    } else {
      u = ustar;
      oi = eqlist[t - n_gt];
    }
    unsigned long long key =
        ((unsigned long long)(~u) << 32) | (unsigned int)oi;
    for (int kk = 2; kk <= 64; kk <<= 1) {
      for (int jj = kk >> 1; jj > 0; jj >>= 1) {
        unsigned long long partner = __shfl_xor(key, jj, 64);
        const bool up = ((t & kk) == 0);
        const bool lower = ((t & jj) == 0);
        unsigned long long mn = key < partner ? key : partner;
        unsigned long long mx = key < partner ? partner : key;
        key = (up == lower) ? mn : mx;
      }
    }
    const unsigned int su = ~(unsigned int)(key >> 32);
    const int so = (int)(key & 0xFFFFFFFFu);
    const float f = (su & 0x80000000u) ? __uint_as_float(su ^ 0x80000000u)
                                       : __uint_as_float(~su);
    out[b * 64 + t] = f;
    out[B_N * 64 + b * 64 + t] = (float)so;
  }
}

// ---------------------------------------------------------------------------
// Fallback: fused single-kernel path (used only if ws is too small).
// ---------------------------------------------------------------------------
template <bool TRANSPOSED>
__global__ __launch_bounds__(256) void selgemv_topk(
    const float* __restrict__ x, const float* __restrict__ Wsrc,
    const float* __restrict__ bias, const int* __restrict__ idx,
    float* __restrict__ out) {
  __shared__ float sx[K_N];
  __shared__ int si[K_N];
  __shared__ float svals[O_N];
  __shared__ unsigned int hist[256];
  __shared__ unsigned int scan[256];
  __shared__ unsigned int sel_u[64];
  __shared__ int sel_i[64];
  __shared__ int eqlist[128];
  __shared__ unsigned int s_T, s_ngt, s_cntgt, s_cnteq;
  __shared__ unsigned int s_remaining, s_prefix;

  const int t = threadIdx.x;
  const int b = blockIdx.x;

  if (t < K_N) {
    sx[t] = x[b * K_N + t];
    si[t] = idx[b * K_N + t];
  }
  if (t == 0) {
    s_remaining = 64u;
    s_prefix = 0u;
    s_cntgt = 0u;
    s_cnteq = 0u;
  }
  __syncthreads();

  float acc[16];
#pragma unroll
  for (int j = 0; j < 16; ++j) acc[j] = 0.0f;

  for (int k = 0; k < K_N; ++k) {
    const float xk = sx[k];
    const int ik = si[k];
    if (TRANSPOSED) {
      const float4* row = (const float4*)(Wsrc + (size_t)ik * O_N);
#pragma unroll
      for (int j = 0; j < 4; ++j) {
        float4 w = row[j * 256 + t];
        acc[4 * j + 0] = __fadd_rn(acc[4 * j + 0], __fmul_rn(xk, w.x));
        acc[4 * j + 1] = __fadd_rn(acc[4 * j + 1], __fmul_rn(xk, w.y));
        acc[4 * j + 2] = __fadd_rn(acc[4 * j + 2], __fmul_rn(xk, w.z));
        acc[4 * j + 3] = __fadd_rn(acc[4 * j + 3], __fmul_rn(xk, w.w));
      }
    } else {
#pragma unroll
      for (int j = 0; j < 4; ++j) {
        int o0 = (j * 256 + t) * 4;
#pragma unroll
        for (int c = 0; c < 4; ++c) {
          float w = Wsrc[(size_t)(o0 + c) * I_N + ik];
          acc[4 * j + c] = __fadd_rn(acc[4 * j + c], __fmul_rn(xk, w));
        }
      }
    }
  }

#pragma unroll
  for (int j = 0; j < 4; ++j) {
    int g = j * 256 + t;
    float4 bb = ((const float4*)bias)[g];
    float4 r;
    r.x = __fadd_rn(acc[4 * j + 0], bb.x);
    r.y = __fadd_rn(acc[4 * j + 1], bb.y);
    r.z = __fadd_rn(acc[4 * j + 2], bb.z);
    r.w = __fadd_rn(acc[4 * j + 3], bb.w);
    ((float4*)svals)[g] = r;
  }
  __syncthreads();

  unsigned int myu[16];
#pragma unroll
  for (int j = 0; j < 16; ++j) {
    float f = svals[t + 256 * j];
    unsigned int s = __float_as_uint(f);
    myu[j] = (s & 0x80000000u) ? ~s : (s | 0x80000000u);
  }

  for (int round = 3; round >= 0; --round) {
    const int shift = round * 8;
    hist[t] = 0u;
    __syncthreads();
    const unsigned int pfx = s_prefix;
    const unsigned int rem = s_remaining;
    const unsigned int himask =
        (round == 3) ? 0u : (0xFFFFFFFFu << (shift + 8));
#pragma unroll
    for (int j = 0; j < 16; ++j) {
      if ((myu[j] & himask) == (pfx & himask))
        atomicAdd(&hist[(myu[j] >> shift) & 255u], 1u);
    }
    __syncthreads();
    scan[t] = hist[t];
    __syncthreads();
    for (int off = 1; off < 256; off <<= 1) {
      unsigned int v = (t + off < 256) ? scan[t + off] : 0u;
      __syncthreads();
      scan[t] += v;
      __syncthreads();
    }
    const unsigned int c_ge = scan[t];
    const unsigned int c_gt = (t < 255) ? scan[t + 1] : 0u;
    if (c_ge >= rem && c_gt < rem) {
      s_T = (unsigned int)t;
      s_ngt = c_gt;
    }
    __syncthreads();
    if (t == 0) {
      s_prefix |= (s_T << shift);
      s_remaining -= s_ngt;
    }
    __syncthreads();
  }
  const unsigned int ustar = s_prefix;

#pragma unroll
  for (int j = 0; j < 16; ++j) {
    const unsigned int u = myu[j];
    if (u > ustar) {
      unsigned int p = atomicAdd(&s_cntgt, 1u);
      sel_u[p] = u;
      sel_i[p] = t + 256 * j;
    } else if (u == ustar) {
      unsigned int p = atomicAdd(&s_cnteq, 1u);
      if (p < 128u) eqlist[p] = t + 256 * j;
    }
  }
  __syncthreads();

  if (t == 0 && s_cnteq > 1u) {
    int n = (int)(s_cnteq < 128u ? s_cnteq : 128u);
    for (int a = 1; a < n; ++a) {
      int v = eqlist[a];
      int c = a;
      while (c > 0 && eqlist[c - 1] > v) {
        eqlist[c] = eqlist[c - 1];
        --c;
      }
      eqlist[c] = v;
    }
  }
  __syncthreads();

  if (t < 64) {
    const int n_gt = (int)s_cntgt;
    unsigned int u;
    int oi;
    if (t < n_gt) {
      u = sel_u[t];
      oi = sel_i[t];
    } else {
      u = ustar;
      oi = eqlist[t - n_gt];
    }
    unsigned long long key =
        ((unsigned long long)(~u) << 32) | (unsigned int)oi;
    for (int kk = 2; kk <= 64; kk <<= 1) {
      for (int jj = kk >> 1; jj > 0; jj >>= 1) {
        unsigned long long partner = __shfl_xor(key, jj, 64);
        const bool up = ((t & kk) == 0);
        const bool lower = ((t & jj) == 0);
        unsigned long long mn = key < partner ? key : partner;
        unsigned long long mx = key < partner ? partner : key;
        key = (up == lower) ? mn : mx;
      }
    }
    const unsigned int su = ~(unsigned int)(key >> 32);
    const int so = (int)(key & 0xFFFFFFFFu);
    const float f = (su & 0x80000000u) ? __uint_as_float(su ^ 0x80000000u)
                                       : __uint_as_float(~su);
    out[b * 64 + t] = f;
    out[B_N * 64 + b * 64 + t] = (float)so;
  }
}

extern "C" void kernel_launch(void* const* d_in, const int* in_sizes, int n_in,
                              void* d_out, int out_size, void* d_ws,
                              size_t ws_size, hipStream_t stream) {
  const float* x = (const float*)d_in[0];     // (1024, 64)
  const float* W = (const float*)d_in[1];     // (4096, 4096)
  const float* bias = (const float*)d_in[2];  // (4096,)
  const int* idx = (const int*)d_in[3];       // (1024, 64) int32
  float* out = (float*)d_out;

  const size_t wt_bytes = (size_t)I_N * O_N * sizeof(float);   // 64 MB
  const size_t res_bytes = (size_t)B_N * O_N * sizeof(float);  // 16 MB

  if (ws_size >= wt_bytes + res_bytes) {
    float* WT = (float*)d_ws;
    float* res = (float*)((char*)d_ws + wt_bytes);
    transpose_kernel<<<dim3(I_N / 64, O_N / 64), 256, 0, stream>>>(W, WT);
    gemv_phase<<<2 * B_N, 256, 0, stream>>>(x, WT, bias, idx, res);
    topk_phase<<<B_N, 256, 0, stream>>>(res, out);
  } else if (ws_size >= wt_bytes) {
    float* WT = (float*)d_ws;
    transpose_kernel<<<dim3(I_N / 64, O_N / 64), 256, 0, stream>>>(W, WT);
    selgemv_topk<true><<<B_N, 256, 0, stream>>>(x, WT, bias, idx, out);
  } else {
    selgemv_topk<false><<<B_N, 256, 0, stream>>>(x, W, bias, idx, out);
  }
}

// Round 3
// 238.122 us; speedup vs baseline: 1.0921x; 1.0921x over previous
//
#include <hip/hip_runtime.h>
#include <stdint.h>

#define B_N 1024
#define K_N 64
#define O_N 4096
#define I_N 4096

// ---------------------------------------------------------------------------
// Transpose W (O x I) -> WT (I x O). 64x64 tiles, float4 global loads/stores.
// ---------------------------------------------------------------------------
__global__ __launch_bounds__(256) void transpose_kernel(
    const float* __restrict__ W, float* __restrict__ WT) {
  __shared__ float tile[64][65];
  const int t = threadIdx.x;
  const int tx = t & 15;
  const int ty = t >> 4;
  const int i0 = blockIdx.x * 64;
  const int o0 = blockIdx.y * 64;
#pragma unroll
  for (int r = 0; r < 4; ++r) {
    const int o = ty + r * 16;
    const float4 v =
        *(const float4*)(W + (size_t)(o0 + o) * I_N + i0 + 4 * tx);
    tile[o][4 * tx + 0] = v.x;
    tile[o][4 * tx + 1] = v.y;
    tile[o][4 * tx + 2] = v.z;
    tile[o][4 * tx + 3] = v.w;
  }
  __syncthreads();
#pragma unroll
  for (int r = 0; r < 4; ++r) {
    const int i = ty + r * 16;
    float4 v;
    v.x = tile[4 * tx + 0][i];
    v.y = tile[4 * tx + 1][i];
    v.z = tile[4 * tx + 2][i];
    v.w = tile[4 * tx + 3][i];
    *(float4*)(WT + (size_t)(i0 + i) * O_N + o0 + 4 * tx) = v;
  }
}

#define ACC4(a, c, xk)                         \
  a.x = __fadd_rn(a.x, __fmul_rn(xk, c.x));    \
  a.y = __fadd_rn(a.y, __fmul_rn(xk, c.y));    \
  a.z = __fadd_rn(a.z, __fmul_rn(xk, c.z));    \
  a.w = __fadd_rn(a.w, __fmul_rn(xk, c.w));

// ---------------------------------------------------------------------------
// Phase 1: gathered matvec. O split in quarters -> 4096 blocks, each thread
// owns one float4 of the output quarter; depth-4 register prefetch pipeline
// for memory-level parallelism. Bit-exact: ascending-k chain, unfused
// mul/add, bias added last.
// ---------------------------------------------------------------------------
__global__ __launch_bounds__(256) void gemv_phase(
    const float* __restrict__ x, const float* __restrict__ WT,
    const float* __restrict__ bias, const int* __restrict__ idx,
    float* __restrict__ res) {
  __shared__ float sx[K_N];
  __shared__ int si[K_N];
  const int t = threadIdx.x;
  const int bb = blockIdx.x;
  const int b = bb >> 2;
  const int q = bb & 3;
  if (t < K_N) {
    sx[t] = x[b * K_N + t];
    si[t] = idx[b * K_N + t];
  }
  __syncthreads();

  const size_t qoff = (size_t)q * 1024 + 4 * t;
  float4 a = make_float4(0.f, 0.f, 0.f, 0.f);
  float4 pf[4];
#pragma unroll
  for (int d = 0; d < 4; ++d)
    pf[d] = *(const float4*)(WT + (size_t)si[d] * O_N + qoff);
#pragma unroll
  for (int k = 0; k < K_N; ++k) {
    const float4 c = pf[k & 3];
    if (k + 4 < K_N)
      pf[k & 3] = *(const float4*)(WT + (size_t)si[k + 4] * O_N + qoff);
    const float xk = sx[k];
    ACC4(a, c, xk);
  }
  const float4 bv = *(const float4*)(bias + qoff);
  a.x = __fadd_rn(a.x, bv.x);
  a.y = __fadd_rn(a.y, bv.y);
  a.z = __fadd_rn(a.z, bv.z);
  a.w = __fadd_rn(a.w, bv.w);
  *(float4*)(res + (size_t)b * O_N + qoff) = a;
}

// ---------------------------------------------------------------------------
// Phase 2: exact top-64 per row. Radix select with single-wave shuffle
// suffix-scan (2 barriers/round), then 64-lane bitonic; ties -> lower index.
// ---------------------------------------------------------------------------
__global__ __launch_bounds__(256) void topk_phase(
    const float* __restrict__ res, float* __restrict__ out) {
  __shared__ __align__(16) unsigned int hist[256];
  __shared__ unsigned int sel_u[64];
  __shared__ int sel_i[64];
  __shared__ int eqlist[128];
  __shared__ unsigned int s_cntgt, s_cnteq;
  __shared__ unsigned int s_remaining, s_prefix;

  const int t = threadIdx.x;
  const int b = blockIdx.x;

  hist[t] = 0u;
  if (t == 0) {
    s_remaining = 64u;
    s_prefix = 0u;
    s_cntgt = 0u;
    s_cnteq = 0u;
  }

  // float4 key loads; element index oi(j) = 4*t + (j&3) + 1024*(j>>2)
  unsigned int myu[16];
#pragma unroll
  for (int jf = 0; jf < 4; ++jf) {
    const float4 v =
        *(const float4*)(res + (size_t)b * O_N + 1024 * jf + 4 * t);
    const float fv[4] = {v.x, v.y, v.z, v.w};
#pragma unroll
    for (int c = 0; c < 4; ++c) {
      const unsigned int s = __float_as_uint(fv[c]);
      myu[jf * 4 + c] = (s & 0x80000000u) ? ~s : (s | 0x80000000u);
    }
  }
  __syncthreads();

  for (int round = 3; round >= 0; --round) {
    const int shift = round * 8;
    const unsigned int pfx = s_prefix;
    const unsigned int rem = s_remaining;
    const unsigned int himask =
        (round == 3) ? 0u : (0xFFFFFFFFu << (shift + 8));
#pragma unroll
    for (int j = 0; j < 16; ++j) {
      if ((myu[j] & himask) == (pfx & himask))
        atomicAdd(&hist[(myu[j] >> shift) & 255u], 1u);
    }
    __syncthreads();
    if (t < 64) {
      // lane t owns bins 4t..4t+3
      const uint4 h = *(const uint4*)&hist[4 * t];
      unsigned int s0 = h.x + h.y + h.z + h.w;
      unsigned int run = s0;
#pragma unroll
      for (int off = 1; off < 64; off <<= 1) {
        const unsigned int v = __shfl_down(run, off, 64);
        if (t + off < 64) run += v;
      }
      const unsigned int above = run - s0;  // sum of bins in lanes > t
      unsigned int cge[4], cgt[4];
      cgt[3] = above;
      cge[3] = above + h.w;
      cgt[2] = cge[3];
      cge[2] = cge[3] + h.z;
      cgt[1] = cge[2];
      cge[1] = cge[2] + h.y;
      cgt[0] = cge[1];
      cge[0] = cge[1] + h.x;
#pragma unroll
      for (int j = 0; j < 4; ++j) {
        if (cge[j] >= rem && cgt[j] < rem) {  // unique crossing bin
          s_prefix = pfx | ((unsigned int)(4 * t + j) << shift);
          s_remaining = rem - cgt[j];
        }
      }
      // clear own bins for next round
      *(uint4*)&hist[4 * t] = make_uint4(0u, 0u, 0u, 0u);
    }
    __syncthreads();
  }
  const unsigned int ustar = s_prefix;

#pragma unroll
  for (int j = 0; j < 16; ++j) {
    const unsigned int u = myu[j];
    const int oi = 4 * t + (j & 3) + 1024 * (j >> 2);
    if (u > ustar) {
      unsigned int p = atomicAdd(&s_cntgt, 1u);
      sel_u[p] = u;
      sel_i[p] = oi;
    } else if (u == ustar) {
      unsigned int p = atomicAdd(&s_cnteq, 1u);
      if (p < 128u) eqlist[p] = oi;
    }
  }
  __syncthreads();

  if (t == 0 && s_cnteq > 1u) {
    int n = (int)(s_cnteq < 128u ? s_cnteq : 128u);
    for (int a = 1; a < n; ++a) {
      int v = eqlist[a];
      int c = a;
      while (c > 0 && eqlist[c - 1] > v) {
        eqlist[c] = eqlist[c - 1];
        --c;
      }
      eqlist[c] = v;
    }
  }
  __syncthreads();

  if (t < 64) {
    const int n_gt = (int)s_cntgt;
    unsigned int u;
    int oi;
    if (t < n_gt) {
      u = sel_u[t];
      oi = sel_i[t];
    } else {
      u = ustar;
      oi = eqlist[t - n_gt];
    }
    unsigned long long key =
        ((unsigned long long)(~u) << 32) | (unsigned int)oi;
    for (int kk = 2; kk <= 64; kk <<= 1) {
      for (int jj = kk >> 1; jj > 0; jj >>= 1) {
        unsigned long long partner = __shfl_xor(key, jj, 64);
        const bool up = ((t & kk) == 0);
        const bool lower = ((t & jj) == 0);
        unsigned long long mn = key < partner ? key : partner;
        unsigned long long mx = key < partner ? partner : key;
        key = (up == lower) ? mn : mx;
      }
    }
    const unsigned int su = ~(unsigned int)(key >> 32);
    const int so = (int)(key & 0xFFFFFFFFu);
    const float f = (su & 0x80000000u) ? __uint_as_float(su ^ 0x80000000u)
                                       : __uint_as_float(~su);
    out[b * 64 + t] = f;
    out[B_N * 64 + b * 64 + t] = (float)so;
  }
}

// ---------------------------------------------------------------------------
// Fallback: fused single-kernel path (used only if ws is too small).
// ---------------------------------------------------------------------------
template <bool TRANSPOSED>
__global__ __launch_bounds__(256) void selgemv_topk(
    const float* __restrict__ x, const float* __restrict__ Wsrc,
    const float* __restrict__ bias, const int* __restrict__ idx,
    float* __restrict__ out) {
  __shared__ float sx[K_N];
  __shared__ int si[K_N];
  __shared__ float svals[O_N];
  __shared__ unsigned int hist[256];
  __shared__ unsigned int scan[256];
  __shared__ unsigned int sel_u[64];
  __shared__ int sel_i[64];
  __shared__ int eqlist[128];
  __shared__ unsigned int s_T, s_ngt, s_cntgt, s_cnteq;
  __shared__ unsigned int s_remaining, s_prefix;

  const int t = threadIdx.x;
  const int b = blockIdx.x;

  if (t < K_N) {
    sx[t] = x[b * K_N + t];
    si[t] = idx[b * K_N + t];
  }
  if (t == 0) {
    s_remaining = 64u;
    s_prefix = 0u;
    s_cntgt = 0u;
    s_cnteq = 0u;
  }
  __syncthreads();

  float acc[16];
#pragma unroll
  for (int j = 0; j < 16; ++j) acc[j] = 0.0f;

  for (int k = 0; k < K_N; ++k) {
    const float xk = sx[k];
    const int ik = si[k];
    if (TRANSPOSED) {
      const float4* row = (const float4*)(Wsrc + (size_t)ik * O_N);
#pragma unroll
      for (int j = 0; j < 4; ++j) {
        float4 w = row[j * 256 + t];
        acc[4 * j + 0] = __fadd_rn(acc[4 * j + 0], __fmul_rn(xk, w.x));
        acc[4 * j + 1] = __fadd_rn(acc[4 * j + 1], __fmul_rn(xk, w.y));
        acc[4 * j + 2] = __fadd_rn(acc[4 * j + 2], __fmul_rn(xk, w.z));
        acc[4 * j + 3] = __fadd_rn(acc[4 * j + 3], __fmul_rn(xk, w.w));
      }
    } else {
#pragma unroll
      for (int j = 0; j < 4; ++j) {
        int o0 = (j * 256 + t) * 4;
#pragma unroll
        for (int c = 0; c < 4; ++c) {
          float w = Wsrc[(size_t)(o0 + c) * I_N + ik];
          acc[4 * j + c] = __fadd_rn(acc[4 * j + c], __fmul_rn(xk, w));
        }
      }
    }
  }

#pragma unroll
  for (int j = 0; j < 4; ++j) {
    int g = j * 256 + t;
    float4 bb = ((const float4*)bias)[g];
    float4 r;
    r.x = __fadd_rn(acc[4 * j + 0], bb.x);
    r.y = __fadd_rn(acc[4 * j + 1], bb.y);
    r.z = __fadd_rn(acc[4 * j + 2], bb.z);
    r.w = __fadd_rn(acc[4 * j + 3], bb.w);
    ((float4*)svals)[g] = r;
  }
  __syncthreads();

  unsigned int myu[16];
#pragma unroll
  for (int j = 0; j < 16; ++j) {
    float f = svals[t + 256 * j];
    unsigned int s = __float_as_uint(f);
    myu[j] = (s & 0x80000000u) ? ~s : (s | 0x80000000u);
  }

  for (int round = 3; round >= 0; --round) {
    const int shift = round * 8;
    hist[t] = 0u;
    __syncthreads();
    const unsigned int pfx = s_prefix;
    const unsigned int rem = s_remaining;
    const unsigned int himask =
        (round == 3) ? 0u : (0xFFFFFFFFu << (shift + 8));
#pragma unroll
    for (int j = 0; j < 16; ++j) {
      if ((myu[j] & himask) == (pfx & himask))
        atomicAdd(&hist[(myu[j] >> shift) & 255u], 1u);
    }
    __syncthreads();
    scan[t] = hist[t];
    __syncthreads();
    for (int off = 1; off < 256; off <<= 1) {
      unsigned int v = (t + off < 256) ? scan[t + off] : 0u;
      __syncthreads();
      scan[t] += v;
      __syncthreads();
    }
    const unsigned int c_ge = scan[t];
    const unsigned int c_gt = (t < 255) ? scan[t + 1] : 0u;
    if (c_ge >= rem && c_gt < rem) {
      s_T = (unsigned int)t;
      s_ngt = c_gt;
    }
    __syncthreads();
    if (t == 0) {
      s_prefix |= (s_T << shift);
      s_remaining -= s_ngt;
    }
    __syncthreads();
  }
  const unsigned int ustar = s_prefix;

#pragma unroll
  for (int j = 0; j < 16; ++j) {
    const unsigned int u = myu[j];
    if (u > ustar) {
      unsigned int p = atomicAdd(&s_cntgt, 1u);
      sel_u[p] = u;
      sel_i[p] = t + 256 * j;
    } else if (u == ustar) {
      unsigned int p = atomicAdd(&s_cnteq, 1u);
      if (p < 128u) eqlist[p] = t + 256 * j;
    }
  }
  __syncthreads();

  if (t == 0 && s_cnteq > 1u) {
    int n = (int)(s_cnteq < 128u ? s_cnteq : 128u);
    for (int a = 1; a < n; ++a) {
      int v = eqlist[a];
      int c = a;
      while (c > 0 && eqlist[c - 1] > v) {
        eqlist[c] = eqlist[c - 1];
        --c;
      }
      eqlist[c] = v;
    }
  }
  __syncthreads();

  if (t < 64) {
    const int n_gt = (int)s_cntgt;
    unsigned int u;
    int oi;
    if (t < n_gt) {
      u = sel_u[t];
      oi = sel_i[t];
    } else {
      u = ustar;
      oi = eqlist[t - n_gt];
    }
    unsigned long long key =
        ((unsigned long long)(~u) << 32) | (unsigned int)oi;
    for (int kk = 2; kk <= 64; kk <<= 1) {
      for (int jj = kk >> 1; jj > 0; jj >>= 1) {
        unsigned long long partner = __shfl_xor(key, jj, 64);
        const bool up = ((t & kk) == 0);
        const bool lower = ((t & jj) == 0);
        unsigned long long mn = key < partner ? key : partner;
        unsigned long long mx = key < partner ? partner : key;
        key = (up == lower) ? mn : mx;
      }
    }
    const unsigned int su = ~(unsigned int)(key >> 32);
    const int so = (int)(key & 0xFFFFFFFFu);
    const float f = (su & 0x80000000u) ? __uint_as_float(su ^ 0x80000000u)
                                       : __uint_as_float(~su);
    out[b * 64 + t] = f;
    out[B_N * 64 + b * 64 + t] = (float)so;
  }
}

extern "C" void kernel_launch(void* const* d_in, const int* in_sizes, int n_in,
                              void* d_out, int out_size, void* d_ws,
                              size_t ws_size, hipStream_t stream) {
  const float* x = (const float*)d_in[0];     // (1024, 64)
  const float* W = (const float*)d_in[1];     // (4096, 4096)
  const float* bias = (const float*)d_in[2];  // (4096,)
  const int* idx = (const int*)d_in[3];       // (1024, 64) int32
  float* out = (float*)d_out;

  const size_t wt_bytes = (size_t)I_N * O_N * sizeof(float);   // 64 MB
  const size_t res_bytes = (size_t)B_N * O_N * sizeof(float);  // 16 MB

  if (ws_size >= wt_bytes + res_bytes) {
    float* WT = (float*)d_ws;
    float* res = (float*)((char*)d_ws + wt_bytes);
    transpose_kernel<<<dim3(I_N / 64, O_N / 64), 256, 0, stream>>>(W, WT);
    gemv_phase<<<4 * B_N, 256, 0, stream>>>(x, WT, bias, idx, res);
    topk_phase<<<B_N, 256, 0, stream>>>(res, out);
  } else if (ws_size >= wt_bytes) {
    float* WT = (float*)d_ws;
    transpose_kernel<<<dim3(I_N / 64, O_N / 64), 256, 0, stream>>>(W, WT);
    selgemv_topk<true><<<B_N, 256, 0, stream>>>(x, WT, bias, idx, out);
  } else {
    selgemv_topk<false><<<B_N, 256, 0, stream>>>(x, W, bias, idx, out);
  }
}

// Round 4
// 229.183 us; speedup vs baseline: 1.1347x; 1.0390x over previous
//
#include <hip/hip_runtime.h>
#include <stdint.h>

#define B_N 1024
#define K_N 64
#define O_N 4096
#define I_N 4096

// ---------------------------------------------------------------------------
// Transpose W (O x I) -> WT (I x O). 64x64 tiles, float4 both ways, batched
// loads/stores so 4 global ops are in flight per thread.
// ---------------------------------------------------------------------------
__global__ __launch_bounds__(256) void transpose_kernel(
    const float* __restrict__ W, float* __restrict__ WT) {
  __shared__ float tile[64][65];
  const int t = threadIdx.x;
  const int tx = t & 15;
  const int ty = t >> 4;
  const int i0 = blockIdx.x * 64;
  const int o0 = blockIdx.y * 64;
  float4 v[4];
#pragma unroll
  for (int r = 0; r < 4; ++r)
    v[r] = *(const float4*)(W + (size_t)(o0 + ty + 16 * r) * I_N + i0 + 4 * tx);
#pragma unroll
  for (int r = 0; r < 4; ++r) {
    const int o = ty + 16 * r;
    tile[o][4 * tx + 0] = v[r].x;
    tile[o][4 * tx + 1] = v[r].y;
    tile[o][4 * tx + 2] = v[r].z;
    tile[o][4 * tx + 3] = v[r].w;
  }
  __syncthreads();
  float4 w[4];
#pragma unroll
  for (int r = 0; r < 4; ++r) {
    const int i = ty + 16 * r;
    w[r].x = tile[4 * tx + 0][i];
    w[r].y = tile[4 * tx + 1][i];
    w[r].z = tile[4 * tx + 2][i];
    w[r].w = tile[4 * tx + 3][i];
  }
#pragma unroll
  for (int r = 0; r < 4; ++r)
    *(float4*)(WT + (size_t)(i0 + ty + 16 * r) * O_N + o0 + 4 * tx) = w[r];
}

#define ACC4(a, c, xk)                         \
  a.x = __fadd_rn(a.x, __fmul_rn(xk, c.x));    \
  a.y = __fadd_rn(a.y, __fmul_rn(xk, c.y));    \
  a.z = __fadd_rn(a.z, __fmul_rn(xk, c.z));    \
  a.w = __fadd_rn(a.w, __fmul_rn(xk, c.w));

// ---------------------------------------------------------------------------
// Phase 1: gathered matvec (quarter per block, depth-8 register pipeline)
// + fused EXACT per-block top-64 (radix select). Emits 64 u64 candidate keys
// per block; global top-64 of a row is a subset of the 4 blocks' top-64s.
// Bit-exact value math: ascending-k chain, unfused mul/add, bias last.
// ---------------------------------------------------------------------------
__global__ __launch_bounds__(256, 4) void gemv_sel(
    const float* __restrict__ x, const float* __restrict__ WT,
    const float* __restrict__ bias, const int* __restrict__ idx,
    unsigned long long* __restrict__ cand) {
  __shared__ float sx[K_N];
  __shared__ int si[K_N];
  __shared__ __align__(16) unsigned int hist[256];
  __shared__ unsigned long long sel[64];
  __shared__ int eqlist[128];
  __shared__ unsigned int s_cntgt, s_cnteq, s_remaining, s_prefix;

  const int t = threadIdx.x;
  const int bb = blockIdx.x;
  const int b = bb >> 2;
  const int q = bb & 3;  // quarter -> XCD pair {q, q+4} via bb%8
  if (t < K_N) {
    sx[t] = x[b * K_N + t];
    si[t] = idx[b * K_N + t];
  }
  hist[t] = 0u;
  if (t == 0) {
    s_cntgt = 0u;
    s_cnteq = 0u;
    s_remaining = 64u;
    s_prefix = 0u;
  }
  __syncthreads();

  const size_t qoff = (size_t)q * 1024 + 4 * t;
  float4 a = make_float4(0.f, 0.f, 0.f, 0.f);
  float4 pf[8];
#pragma unroll
  for (int d = 0; d < 8; ++d)
    pf[d] = *(const float4*)(WT + (size_t)si[d] * O_N + qoff);
#pragma unroll
  for (int k = 0; k < K_N; ++k) {
    const float4 c = pf[k & 7];
    if (k + 8 < K_N)
      pf[k & 7] = *(const float4*)(WT + (size_t)si[k + 8] * O_N + qoff);
    const float xk = sx[k];
    ACC4(a, c, xk);
  }
  const float4 bv = *(const float4*)(bias + qoff);
  a.x = __fadd_rn(a.x, bv.x);
  a.y = __fadd_rn(a.y, bv.y);
  a.z = __fadd_rn(a.z, bv.z);
  a.w = __fadd_rn(a.w, bv.w);

  // monotone keys for the 4 owned outputs
  const float fv[4] = {a.x, a.y, a.z, a.w};
  unsigned int u[4];
#pragma unroll
  for (int c = 0; c < 4; ++c) {
    const unsigned int s = __float_as_uint(fv[c]);
    u[c] = (s & 0x80000000u) ? ~s : (s | 0x80000000u);
  }

  // ---- radix select top-64 of this block's 1024 values ----
  for (int round = 3; round >= 0; --round) {
    const int shift = round * 8;
    const unsigned int pfx = s_prefix;
    const unsigned int rem = s_remaining;
    const unsigned int himask =
        (round == 3) ? 0u : (0xFFFFFFFFu << (shift + 8));
#pragma unroll
    for (int c = 0; c < 4; ++c) {
      if ((u[c] & himask) == (pfx & himask))
        atomicAdd(&hist[(u[c] >> shift) & 255u], 1u);
    }
    __syncthreads();
    if (t < 64) {
      const uint4 h = *(const uint4*)&hist[4 * t];
      const unsigned int s0 = h.x + h.y + h.z + h.w;
      unsigned int run = s0;
#pragma unroll
      for (int off = 1; off < 64; off <<= 1) {
        const unsigned int v = __shfl_down(run, off, 64);
        if (t + off < 64) run += v;
      }
      const unsigned int above = run - s0;
      unsigned int cge[4], cgt[4];
      cgt[3] = above;
      cge[3] = above + h.w;
      cgt[2] = cge[3];
      cge[2] = cge[3] + h.z;
      cgt[1] = cge[2];
      cge[1] = cge[2] + h.y;
      cgt[0] = cge[1];
      cge[0] = cge[1] + h.x;
#pragma unroll
      for (int j = 0; j < 4; ++j) {
        if (cge[j] >= rem && cgt[j] < rem) {
          s_prefix = pfx | ((unsigned int)(4 * t + j) << shift);
          s_remaining = rem - cgt[j];
        }
      }
      *(uint4*)&hist[4 * t] = make_uint4(0u, 0u, 0u, 0u);
    }
    __syncthreads();
  }
  const unsigned int ustar = s_prefix;

#pragma unroll
  for (int c = 0; c < 4; ++c) {
    const int oi = (int)qoff + c;
    if (u[c] > ustar) {
      unsigned int p = atomicAdd(&s_cntgt, 1u);
      sel[p] = ((unsigned long long)(~u[c]) << 32) | (unsigned int)oi;
    } else if (u[c] == ustar) {
      unsigned int p = atomicAdd(&s_cnteq, 1u);
      if (p < 128u) eqlist[p] = oi;
    }
  }
  __syncthreads();

  if (t == 0 && s_cnteq > 1u) {
    int n = (int)(s_cnteq < 128u ? s_cnteq : 128u);
    for (int aa = 1; aa < n; ++aa) {
      int v = eqlist[aa];
      int c = aa;
      while (c > 0 && eqlist[c - 1] > v) {
        eqlist[c] = eqlist[c - 1];
        --c;
      }
      eqlist[c] = v;
    }
  }
  __syncthreads();

  if (t < 64) {
    const int n_gt = (int)s_cntgt;  // <= 63 by select invariant
    unsigned long long key;
    if (t < n_gt)
      key = sel[t];
    else
      key = ((unsigned long long)(~ustar) << 32) |
            (unsigned int)eqlist[t - n_gt];
    cand[(size_t)bb * 64 + t] = key;  // unsorted; merge kernel sorts
  }
}

// ---------------------------------------------------------------------------
// Phase 2: merge 4x64 candidates per row -> exact top-64 via bitonic sort of
// 256 u64 keys (shuffle for j<64, LDS for j>=64). Ascending key order ==
// value desc, index asc on ties (matches jax.lax.top_k).
// ---------------------------------------------------------------------------
__global__ __launch_bounds__(256) void merge_topk(
    const unsigned long long* __restrict__ cand, float* __restrict__ out) {
  __shared__ unsigned long long sk[256];
  const int t = threadIdx.x;
  const int b = blockIdx.x;
  unsigned long long key = cand[(size_t)b * 256 + t];
#pragma unroll
  for (int k = 2; k <= 256; k <<= 1) {
#pragma unroll
    for (int j = k >> 1; j > 0; j >>= 1) {
      unsigned long long partner;
      if (j >= 64) {
        sk[t] = key;
        __syncthreads();
        partner = sk[t ^ j];
        __syncthreads();
      } else {
        partner = __shfl_xor(key, j, 64);
      }
      const bool up = ((t & k) == 0);
      const bool lower = ((t & j) == 0);
      const unsigned long long mn = key < partner ? key : partner;
      const unsigned long long mx = key < partner ? partner : key;
      key = (up == lower) ? mn : mx;
    }
  }
  if (t < 64) {
    const unsigned int su = ~(unsigned int)(key >> 32);
    const int so = (int)(key & 0xFFFFFFFFu);
    const float f = (su & 0x80000000u) ? __uint_as_float(su ^ 0x80000000u)
                                       : __uint_as_float(~su);
    out[b * 64 + t] = f;
    out[B_N * 64 + b * 64 + t] = (float)so;
  }
}

// ---------------------------------------------------------------------------
// Fallback: fused single-kernel path (used only if ws is too small).
// ---------------------------------------------------------------------------
template <bool TRANSPOSED>
__global__ __launch_bounds__(256) void selgemv_topk(
    const float* __restrict__ x, const float* __restrict__ Wsrc,
    const float* __restrict__ bias, const int* __restrict__ idx,
    float* __restrict__ out) {
  __shared__ float sx[K_N];
  __shared__ int si[K_N];
  __shared__ float svals[O_N];
  __shared__ unsigned int hist[256];
  __shared__ unsigned int scan[256];
  __shared__ unsigned int sel_u[64];
  __shared__ int sel_i[64];
  __shared__ int eqlist[128];
  __shared__ unsigned int s_T, s_ngt, s_cntgt, s_cnteq;
  __shared__ unsigned int s_remaining, s_prefix;

  const int t = threadIdx.x;
  const int b = blockIdx.x;

  if (t < K_N) {
    sx[t] = x[b * K_N + t];
    si[t] = idx[b * K_N + t];
  }
  if (t == 0) {
    s_remaining = 64u;
    s_prefix = 0u;
    s_cntgt = 0u;
    s_cnteq = 0u;
  }
  __syncthreads();

  float acc[16];
#pragma unroll
  for (int j = 0; j < 16; ++j) acc[j] = 0.0f;

  for (int k = 0; k < K_N; ++k) {
    const float xk = sx[k];
    const int ik = si[k];
    if (TRANSPOSED) {
      const float4* row = (const float4*)(Wsrc + (size_t)ik * O_N);
#pragma unroll
      for (int j = 0; j < 4; ++j) {
        float4 w = row[j * 256 + t];
        acc[4 * j + 0] = __fadd_rn(acc[4 * j + 0], __fmul_rn(xk, w.x));
        acc[4 * j + 1] = __fadd_rn(acc[4 * j + 1], __fmul_rn(xk, w.y));
        acc[4 * j + 2] = __fadd_rn(acc[4 * j + 2], __fmul_rn(xk, w.z));
        acc[4 * j + 3] = __fadd_rn(acc[4 * j + 3], __fmul_rn(xk, w.w));
      }
    } else {
#pragma unroll
      for (int j = 0; j < 4; ++j) {
        int o0 = (j * 256 + t) * 4;
#pragma unroll
        for (int c = 0; c < 4; ++c) {
          float w = Wsrc[(size_t)(o0 + c) * I_N + ik];
          acc[4 * j + c] = __fadd_rn(acc[4 * j + c], __fmul_rn(xk, w));
        }
      }
    }
  }

#pragma unroll
  for (int j = 0; j < 4; ++j) {
    int g = j * 256 + t;
    float4 bb = ((const float4*)bias)[g];
    float4 r;
    r.x = __fadd_rn(acc[4 * j + 0], bb.x);
    r.y = __fadd_rn(acc[4 * j + 1], bb.y);
    r.z = __fadd_rn(acc[4 * j + 2], bb.z);
    r.w = __fadd_rn(acc[4 * j + 3], bb.w);
    ((float4*)svals)[g] = r;
  }
  __syncthreads();

  unsigned int myu[16];
#pragma unroll
  for (int j = 0; j < 16; ++j) {
    float f = svals[t + 256 * j];
    unsigned int s = __float_as_uint(f);
    myu[j] = (s & 0x80000000u) ? ~s : (s | 0x80000000u);
  }

  for (int round = 3; round >= 0; --round) {
    const int shift = round * 8;
    hist[t] = 0u;
    __syncthreads();
    const unsigned int pfx = s_prefix;
    const unsigned int rem = s_remaining;
    const unsigned int himask =
        (round == 3) ? 0u : (0xFFFFFFFFu << (shift + 8));
#pragma unroll
    for (int j = 0; j < 16; ++j) {
      if ((myu[j] & himask) == (pfx & himask))
        atomicAdd(&hist[(myu[j] >> shift) & 255u], 1u);
    }
    __syncthreads();
    scan[t] = hist[t];
    __syncthreads();
    for (int off = 1; off < 256; off <<= 1) {
      unsigned int v = (t + off < 256) ? scan[t + off] : 0u;
      __syncthreads();
      scan[t] += v;
      __syncthreads();
    }
    const unsigned int c_ge = scan[t];
    const unsigned int c_gt = (t < 255) ? scan[t + 1] : 0u;
    if (c_ge >= rem && c_gt < rem) {
      s_T = (unsigned int)t;
      s_ngt = c_gt;
    }
    __syncthreads();
    if (t == 0) {
      s_prefix |= (s_T << shift);
      s_remaining -= s_ngt;
    }
    __syncthreads();
  }
  const unsigned int ustar = s_prefix;

#pragma unroll
  for (int j = 0; j < 16; ++j) {
    const unsigned int u = myu[j];
    if (u > ustar) {
      unsigned int p = atomicAdd(&s_cntgt, 1u);
      sel_u[p] = u;
      sel_i[p] = t + 256 * j;
    } else if (u == ustar) {
      unsigned int p = atomicAdd(&s_cnteq, 1u);
      if (p < 128u) eqlist[p] = t + 256 * j;
    }
  }
  __syncthreads();

  if (t == 0 && s_cnteq > 1u) {
    int n = (int)(s_cnteq < 128u ? s_cnteq : 128u);
    for (int a = 1; a < n; ++a) {
      int v = eqlist[a];
      int c = a;
      while (c > 0 && eqlist[c - 1] > v) {
        eqlist[c] = eqlist[c - 1];
        --c;
      }
      eqlist[c] = v;
    }
  }
  __syncthreads();

  if (t < 64) {
    const int n_gt = (int)s_cntgt;
    unsigned int u;
    int oi;
    if (t < n_gt) {
      u = sel_u[t];
      oi = sel_i[t];
    } else {
      u = ustar;
      oi = eqlist[t - n_gt];
    }
    unsigned long long key =
        ((unsigned long long)(~u) << 32) | (unsigned int)oi;
    for (int kk = 2; kk <= 64; kk <<= 1) {
      for (int jj = kk >> 1; jj > 0; jj >>= 1) {
        unsigned long long partner = __shfl_xor(key, jj, 64);
        const bool up = ((t & kk) == 0);
        const bool lower = ((t & jj) == 0);
        unsigned long long mn = key < partner ? key : partner;
        unsigned long long mx = key < partner ? partner : key;
        key = (up == lower) ? mn : mx;
      }
    }
    const unsigned int su = ~(unsigned int)(key >> 32);
    const int so = (int)(key & 0xFFFFFFFFu);
    const float f = (su & 0x80000000u) ? __uint_as_float(su ^ 0x80000000u)
                                       : __uint_as_float(~su);
    out[b * 64 + t] = f;
    out[B_N * 64 + b * 64 + t] = (float)so;
  }
}

extern "C" void kernel_launch(void* const* d_in, const int* in_sizes, int n_in,
                              void* d_out, int out_size, void* d_ws,
                              size_t ws_size, hipStream_t stream) {
  const float* x = (const float*)d_in[0];     // (1024, 64)
  const float* W = (const float*)d_in[1];     // (4096, 4096)
  const float* bias = (const float*)d_in[2];  // (4096,)
  const int* idx = (const int*)d_in[3];       // (1024, 64) int32
  float* out = (float*)d_out;

  const size_t wt_bytes = (size_t)I_N * O_N * sizeof(float);  // 64 MB
  const size_t cand_bytes = (size_t)4 * B_N * 64 * 8;         // 2 MB

  if (ws_size >= wt_bytes + cand_bytes) {
    float* WT = (float*)d_ws;
    unsigned long long* cand = (unsigned long long*)((char*)d_ws + wt_bytes);
    transpose_kernel<<<dim3(I_N / 64, O_N / 64), 256, 0, stream>>>(W, WT);
    gemv_sel<<<4 * B_N, 256, 0, stream>>>(x, WT, bias, idx, cand);
    merge_topk<<<B_N, 256, 0, stream>>>(cand, out);
  } else if (ws_size >= wt_bytes) {
    float* WT = (float*)d_ws;
    transpose_kernel<<<dim3(I_N / 64, O_N / 64), 256, 0, stream>>>(W, WT);
    selgemv_topk<true><<<B_N, 256, 0, stream>>>(x, WT, bias, idx, out);
  } else {
    selgemv_topk<false><<<B_N, 256, 0, stream>>>(x, W, bias, idx, out);
  }
}